// Round 6
// baseline (463.317 us; speedup 1.0000x reference)
//
#include <hip/hip_runtime.h>

typedef unsigned char  u8;
typedef unsigned short u16;
typedef unsigned int   u32;

#define NN   16384     // nodes
#define EE   262144    // edges
#define RR   9         // relations
#define DIN  384
#define DH   768
#define KSU  3456      // RR*DIN
#define KS   3488      // KSU + 9 cnt cols + pad to 32
#define NPB  2         // nodes per block in phase2
#define PCOP 16        // partial pooled copies

typedef float  f32x4 __attribute__((ext_vector_type(4)));
typedef float  f32x2 __attribute__((ext_vector_type(2)));
typedef u32    u32x2 __attribute__((ext_vector_type(2)));
typedef __bf16 b16x8 __attribute__((ext_vector_type(8)));

__device__ __forceinline__ u16 f2bf(float f){
  u32 u = __builtin_bit_cast(u32, f);
  u += 0x7fffu + ((u >> 16) & 1u);          // RNE
  return (u16)(u >> 16);
}
__device__ __forceinline__ float bf2f(u16 h){
  u32 u = ((u32)h) << 16;
  return __builtin_bit_cast(float, u);
}
__device__ __forceinline__ u32 pkbf(float a, float b){
  return (u32)f2bf(a) | ((u32)f2bf(b) << 16);
}
// async global->LDS, 16B per lane; LDS dest = wave-uniform base + lane*16
__device__ __forceinline__ void gll16(const void* g, void* l){
  __builtin_amdgcn_global_load_lds((const __attribute__((address_space(1))) void*)g,
                                   (__attribute__((address_space(3))) void*)l, 16, 0, 0);
}
// DPP row rotate (16-lane rows), full-rate VALU — no LDS pipe
template<int N> __device__ __forceinline__ float dppror(float v){
  return __builtin_bit_cast(float,
    __builtin_amdgcn_update_dpp(0, __builtin_bit_cast(int, v), 0x120+N, 0xF, 0xF, true));
}
__device__ __forceinline__ float swz16(float v){   // lane ^ 16 within 32-group
  return __builtin_bit_cast(float,
    __builtin_amdgcn_ds_swizzle(__builtin_bit_cast(int, v), 0x401F));
}

// ---------------- CSR build ----------------
__global__ void k_count(const int* __restrict__ dst, int* __restrict__ counts){
  const int e = blockIdx.x*256 + threadIdx.x;
  if (e < EE) atomicAdd(&counts[dst[e]], 1);
}

__global__ __launch_bounds__(1024) void k_scan(const int* __restrict__ counts,
                                               int* __restrict__ starts,
                                               int* __restrict__ cursor){
  __shared__ int tot[1024];
  const int t = threadIdx.x;
  int loc[16]; int s = 0;
  #pragma unroll
  for (int j=0;j<16;j++){ loc[j] = counts[t*16+j]; s += loc[j]; }
  tot[t] = s;
  __syncthreads();
  for (int o=1;o<1024;o<<=1){
    int v = (t>=o) ? tot[t-o] : 0;
    __syncthreads();
    tot[t] += v;
    __syncthreads();
  }
  int run = tot[t] - s;  // exclusive prefix
  #pragma unroll
  for (int j=0;j<16;j++){ starts[t*16+j] = run; cursor[t*16+j] = run; run += loc[j]; }
  if (t == 1023) starts[NN] = run;
}

// scatter edges into CSR order; pack src | (rel<<28) into one array
__global__ void k_place(const int* __restrict__ src, const int* __restrict__ dst,
                        const int* __restrict__ et, int* __restrict__ cursor,
                        int* __restrict__ sp){
  const int e = blockIdx.x*256 + threadIdx.x;
  if (e < EE){
    const int p = atomicAdd(&cursor[dst[e]], 1);
    sp[p] = (int)(((u32)et[e] << 28) | (u32)src[e]);
  }
}

// ---------------- weight conversion to bf16 ----------------
__global__ void k_convW1(const float* __restrict__ rW, const float* __restrict__ rb,
                         u16* __restrict__ Wst){
  const int hh = blockIdx.y;
  const int k  = blockIdx.x*256 + threadIdx.x;
  if (k >= KS) return;
  float v;
  if (k < KSU){ const int r = k / DIN; const int d = k - r*DIN;
                v = rW[((long)r*DH + hh)*DIN + d]; }
  else if (k < KSU + RR){ const int r = k - KSU; v = rb[(long)r*DH + hh]; }
  else v = 0.f;
  Wst[(long)hh*KS + k] = f2bf(v);
}

__global__ void k_convW2(const float* __restrict__ lW, const float* __restrict__ sW,
                         u16* __restrict__ WB){
  const int idx = blockIdx.x*256 + threadIdx.x;  // exactly 1179648 threads
  const float v = (idx < DH*DH) ? lW[idx] : sW[idx - DH*DH];
  WB[idx] = f2bf(v);
}

// ---------------- phase1 fused: one wave per dst node, VGPR accumulators ----
__global__ __launch_bounds__(256, 3) void k_phase1f(const float* __restrict__ x,
                                                    const int* __restrict__ sp,
                                                    const float* __restrict__ nc,
                                                    const int* __restrict__ starts,
                                                    u16* __restrict__ s){
  const int wv = threadIdx.x >> 6;
  const int l  = threadIdx.x & 63;
  const int i  = blockIdx.x*4 + wv;
  const float* xdp = x + (long)i*DIN;
  const f32x4 xq = *(const f32x4*)(xdp + 4*l);
  const f32x2 xr = *(const f32x2*)(xdp + 256 + 2*l);
  float acc[RR][6];
  float cacc[RR];
  #pragma unroll
  for (int r=0;r<RR;r++){
    cacc[r] = 0.f;
    #pragma unroll
    for (int j=0;j<6;j++) acc[r][j] = 0.f;
  }
  const int e0 = starts[i], e1 = starts[i+1];
  f32x4 Aq={0,0,0,0}, Bq={0,0,0,0}, Cq={0,0,0,0}, Dq={0,0,0,0};
  f32x2 Ar={0,0}, Br={0,0}, Cr={0,0}, Dr={0,0};
  u32 qA=0,qB=0,qC=0,qD=0;
  #define LDE(S, QQ, IDX) { const int pe_=(IDX); if (pe_ < e1){ QQ = (u32)sp[pe_]; \
      const float* xs_ = x + (long)(QQ & 0x3FFFu)*DIN; \
      S##q = *(const f32x4*)(xs_ + 4*l); \
      S##r = *(const f32x2*)(xs_ + 256 + 2*l); } }
  LDE(A,qA,e0) LDE(B,qB,e0+1) LDE(C,qC,e0+2) LDE(D,qD,e0+3)
  #define DOT(uq,ur) (xq.x*uq.x + xq.y*uq.y + xq.z*uq.z + xq.w*uq.w \
                    + xr.x*ur.x + xr.y*ur.y)
  #define UPD(R,P,cq,cr) { cacc[R] += P; \
      acc[R][0] += P*cq.x; acc[R][1] += P*cq.y; acc[R][2] += P*cq.z; \
      acc[R][3] += P*cq.w; acc[R][4] += P*cr.x; acc[R][5] += P*cr.y; }
  #define SW(RQ,P,cq,cr) switch (RQ){ \
      case 0: UPD(0,P,cq,cr); break; case 1: UPD(1,P,cq,cr); break; \
      case 2: UPD(2,P,cq,cr); break; case 3: UPD(3,P,cq,cr); break; \
      case 4: UPD(4,P,cq,cr); break; case 5: UPD(5,P,cq,cr); break; \
      case 6: UPD(6,P,cq,cr); break; case 7: UPD(7,P,cq,cr); break; \
      default: UPD(8,P,cq,cr); break; }
  for (int p=e0; p<e1; p+=4){
    const f32x4 aq=Aq, bq=Bq, cq=Cq, dq=Dq;
    const f32x2 ar=Ar, br=Br, cr=Cr, dr=Dr;
    const u32 qa=qA, qb=qB, qc=qC, qd=qD;
    const bool h1 = p+1<e1, h2 = p+2<e1, h3 = p+3<e1;
    LDE(A,qA,p+4) LDE(B,qB,p+5) LDE(C,qC,p+6) LDE(D,qD,p+7)
    float pa = DOT(aq,ar), pb = DOT(bq,br);
    float pc = DOT(cq,cr), pd = DOT(dq,dr);
    // 16-lane rotate-reduce via DPP (VALU), then xor16 (swizzle), xor32 (shfl)
    pa += dppror<1>(pa); pb += dppror<1>(pb); pc += dppror<1>(pc); pd += dppror<1>(pd);
    pa += dppror<2>(pa); pb += dppror<2>(pb); pc += dppror<2>(pc); pd += dppror<2>(pd);
    pa += dppror<4>(pa); pb += dppror<4>(pb); pc += dppror<4>(pc); pd += dppror<4>(pd);
    pa += dppror<8>(pa); pb += dppror<8>(pb); pc += dppror<8>(pc); pd += dppror<8>(pd);
    pa += swz16(pa); pb += swz16(pb); pc += swz16(pc); pd += swz16(pd);
    pa += __shfl_xor(pa,32); pb += __shfl_xor(pb,32);
    pc += __shfl_xor(pc,32); pd += __shfl_xor(pd,32);
    SW(qa>>28, pa, aq,ar);
    if (h1){ SW(qb>>28, pb, bq,br); }
    if (h2){ SW(qc>>28, pc, cq,cr); }
    if (h3){ SW(qd>>28, pd, dq,dr); }
  }
  #undef LDE
  #undef DOT
  #undef UPD
  #undef SW
  u16* srow = s + (long)i*KS;
  #pragma unroll
  for (int r=0;r<RR;r++){
    const float inv = 1.0f / nc[r];
    const u32 pk0 = pkbf(acc[r][0]*inv, acc[r][1]*inv);
    const u32 pk1 = pkbf(acc[r][2]*inv, acc[r][3]*inv);
    const u32 pk2 = pkbf(acc[r][4]*inv, acc[r][5]*inv);
    *(u32x2*)(srow + r*DIN + 4*l) = (u32x2){pk0, pk1};   // cols 4l..4l+3
    ((u32*)(srow + r*DIN + 256))[l] = pk2;               // cols 256+{2l,2l+1}
  }
  float cv = 0.f;
  #pragma unroll
  for (int r=0;r<RR;r++) cv = (l == r) ? cacc[r] : cv;
  if (l < 32){
    const float invl = (l < RR) ? 1.0f/nc[l] : 0.f;
    srow[KSU + l] = f2bf(l < RR ? cv*invl : 0.f);
  }
}

// ---------------- 256x128 ring-pipelined bf16 GEMM: C = A * B^T (K-major) -----
// 512 threads = 8 waves (4 wm x 2 wn), per-wave C = 64x64 (acc[4][4] = 64 AGPR).
// BK=32; 3-slot LDS ring, 24 KiB/slot (A 16K + B 8K) = 72 KiB total -> 2
// blocks/CU; prefetch distance 2; ONE raw s_barrier + ONE counted
// s_waitcnt vmcnt(3) per K-tile (3 loads/tile/thread; next tile's 3 loads stay
// in flight across every barrier — T4, never 0 in steady state).
// K-slot XOR swizzle (unit ^= (row>>1)&3) via inverse-swizzled GLOBAL source
// (gll16 dest linear) + swizzled ds_read (T2, 0-conflict proven in R4/R5).
// KEY: swizzle unit fq^((row>>1)&3) is ROW-INVARIANT per thread (wm*64, i*16
// are 0 mod 8), so all fragment reads share ONE LDS base + imm offsets.
// setprio around MFMA cluster (T5).
// Race-freedom: STAGE(tt+2) writes slot (tt+2)%3 == (tt-1)%3, whose readers
// all finished before the barrier that ended iteration tt-1.
// 1-D grid, bijective XCD-chunk swizzle (nwg%8==0, cpx%NT==0): all NT n-tiles
// of an A-panel on one XCD; gemm1's 384 blocks are 100% co-resident at 2/CU.
// MODE 0: O0 = relu(C) bf16 (gemm1) ; MODE 1: n<768 -> O0=C+b0 else O1=C+b1
template<int MODE, int NT>
__global__ __launch_bounds__(512, 4)
void k_gemmw(const u16* __restrict__ A, const u16* __restrict__ B, int K,
             u16* __restrict__ O0, u16* __restrict__ O1,
             const float* __restrict__ b0, const float* __restrict__ b1)
{
  __shared__ __align__(16) u16 lds[3][(256+128)*32];   // 72 KiB total
  const int cpx = gridDim.x >> 3;
  const int bid = blockIdx.x;
  const int lg  = (bid & 7)*cpx + (bid >> 3);
  const int mt  = lg / NT;
  const long m0 = (long)mt * 256;
  const long n0 = (long)(lg - mt*NT) * 128;
  const int t   = threadIdx.x;
  const int wv  = t >> 6;
  const int ln  = t & 63;
  const int wm  = wv >> 1;          // 0..3
  const int wn  = wv & 1;           // 0..1
  const int fr  = ln & 15, fq = ln >> 4;

  // staging: thread t covers rows arow, arow+128 of A and row arow of B;
  // LDS k-unit = t&3 (linear dest); global k-unit = (t&3) ^ ((arow>>1)&3).
  const int arow = t >> 2;          // 0..127
  const int gsl  = (t & 3) ^ ((arow >> 1) & 3);

  // fragment ds_read bases (bytes within a slot); swizzle unit is row-invariant
  const int su    = fq ^ ((fr >> 1) & 3);
  const int dsA   = (wm*64 + fr)*64 + (su << 4);            // A: row*64
  const int dsB   = 16384 + (wn*64 + fr)*64 + (su << 4);    // B at +16 KiB

  f32x4 acc[4][4];
  #pragma unroll
  for (int i=0;i<4;i++)
    #pragma unroll
    for (int j=0;j<4;j++) acc[i][j] = {0.f,0.f,0.f,0.f};

  const int nk = K >> 5;

  #define STAGE(SL, TT) { const long k0_ = (long)(TT)*32;                         \
    u16* s_ = &lds[SL][0];                                                        \
    gll16(A + (m0 +       arow)*(long)K + k0_ + gsl*8, s_ + wv*512);              \
    gll16(A + (m0 + 128 + arow)*(long)K + k0_ + gsl*8, s_ + 4096 + wv*512);       \
    gll16(B + (n0 +       arow)*(long)K + k0_ + gsl*8, s_ + 8192 + wv*512); }

  STAGE(0, 0) STAGE(1, 1)
  asm volatile("s_waitcnt vmcnt(3)" ::: "memory");   // tile 0 landed; 1 in flight
  __builtin_amdgcn_s_barrier();

  int cs = 0, ps = 2;                                 // compute slot, prefetch slot
  for (int tt = 0; tt < nk; ++tt){
    if (tt + 2 < nk) STAGE(ps, tt + 2)
    const u8* sl = (const u8*)&lds[cs][0];
    b16x8 av[4], bv[4];
    #pragma unroll
    for (int i=0;i<4;i++) av[i] = *(const b16x8*)(sl + dsA + i*1024);
    #pragma unroll
    for (int j=0;j<4;j++) bv[j] = *(const b16x8*)(sl + dsB + j*1024);
    __builtin_amdgcn_s_setprio(1);
    #pragma unroll
    for (int i=0;i<4;i++)
      #pragma unroll
      for (int j=0;j<4;j++)
        acc[i][j] = __builtin_amdgcn_mfma_f32_16x16x32_bf16(av[i], bv[j], acc[i][j], 0, 0, 0);
    __builtin_amdgcn_s_setprio(0);
    if (tt + 2 < nk)      asm volatile("s_waitcnt vmcnt(3)" ::: "memory");
    else if (tt + 1 < nk) asm volatile("s_waitcnt vmcnt(0)" ::: "memory");
    __builtin_amdgcn_s_barrier();
    cs = (cs == 2) ? 0 : cs + 1;
    ps = (ps == 2) ? 0 : ps + 1;
  }
  #undef STAGE

  #pragma unroll
  for (int i=0;i<4;i++){
    #pragma unroll
    for (int j=0;j<4;j++){
      #pragma unroll
      for (int r=0;r<4;r++){
        const long m = m0 + wm*64 + i*16 + fq*4 + r;   // C row = quad*4+reg
        const long n = n0 + wn*64 + j*16 + fr;         // C col = lane&15
        float v = acc[i][j][r];
        if (MODE == 0){
          v = v > 0.f ? v : 0.f;
          O0[m*DH + n] = f2bf(v);
        } else {
          if (n < DH) O0[m*DH + n]      = f2bf(v + b0[n]);
          else        O1[m*DH + (n-DH)] = f2bf(v + b1[n-DH]);
        }
      }
    }
  }
}

// ---------------- phase2 fused with mean-pool: aggr2 + self + relu -> pooled ----
// NPB nodes per 128-thread block (NPB=2 -> 8192 blocks of TLP for the
// L3-latency-bound gather); flat edge stream, 8-slot pipeline (depth 8).
__global__ __launch_bounds__(128) void k_phase2(const u16* __restrict__ hm,
                                                const u16* __restrict__ sfx,
                                                const int* __restrict__ sp,
                                                const int* __restrict__ starts,
                                                float* __restrict__ pooledP){
  const int t  = threadIdx.x;
  const int i0 = blockIdx.x * NPB;
  const int p0 = starts[i0];
  const int pend = starts[i0 + NPB];
  u32 sf00,sf01,sf02, sf10,sf11,sf12;
  { const u32* sr = (const u32*)(sfx + (long)(i0+0)*DH); sf00=sr[t]; sf01=sr[t+128]; sf02=sr[t+256]; }
  { const u32* sr = (const u32*)(sfx + (long)(i0+1)*DH); sf10=sr[t]; sf11=sr[t+128]; sf12=sr[t+256]; }
  u32 A0=0,A1=0,A2=0,B0=0,B1=0,B2=0,C0=0,C1=0,C2=0,D0=0,D1=0,D2=0;
  u32 E0=0,E1=0,E2=0,F0=0,F1=0,F2=0,G0=0,G1=0,G2=0,H0=0,H1=0,H2=0;
  #define PLD(S, IDX) { const int nf_=(IDX); if (nf_ < pend){ \
      const u32* hr_ = (const u32*)(hm + (long)(((u32)sp[nf_]) & 0x3FFFu)*DH); \
      S##0=hr_[t]; S##1=hr_[t+128]; S##2=hr_[t+256]; } }
  PLD(A,p0)   PLD(B,p0+1) PLD(C,p0+2) PLD(D,p0+3)
  PLD(E,p0+4) PLD(F,p0+5) PLD(G,p0+6) PLD(H,p0+7)
  float a0=0.f,a1=0.f,a2=0.f,a3=0.f,a4=0.f,a5=0.f;
  float q0=0.f,q1=0.f,q2=0.f,q3=0.f,q4=0.f,q5=0.f;
  int i = i0;
  int e1 = starts[i0+1];
  #define FLUSH(K) { float v_; \
    v_=a0+bf2f((u16)sf##K##0);        q0+=fmaxf(v_,0.f); \
    v_=a1+bf2f((u16)(sf##K##0>>16));  q1+=fmaxf(v_,0.f); \
    v_=a2+bf2f((u16)sf##K##1);        q2+=fmaxf(v_,0.f); \
    v_=a3+bf2f((u16)(sf##K##1>>16));  q3+=fmaxf(v_,0.f); \
    v_=a4+bf2f((u16)sf##K##2);        q4+=fmaxf(v_,0.f); \
    v_=a5+bf2f((u16)(sf##K##2>>16));  q5+=fmaxf(v_,0.f); \
    a0=a1=a2=a3=a4=a5=0.f; }
  #define FLUSHI { if (i == i0){ FLUSH(0); } else { FLUSH(1); } }
  while (i < i0+NPB && e1 == p0){ FLUSHI; ++i; e1 = (i < i0+NPB) ? starts[i+1] : 0x7fffffff; }
  #define STEP(S, K) { const int pe_ = base + K; if (pe_ < pend){ \
      const u32 d0_=S##0, d1_=S##1, d2_=S##2; \
      PLD(S, pe_ + 8); \
      a0+=bf2f((u16)d0_); a1+=bf2f((u16)(d0_>>16)); \
      a2+=bf2f((u16)d1_); a3+=bf2f((u16)(d1_>>16)); \
      a4+=bf2f((u16)d2_); a5+=bf2f((u16)(d2_>>16)); \
      while (i < i0+NPB && pe_+1 == e1){ FLUSHI; ++i; \
        e1 = (i < i0+NPB) ? starts[i+1] : 0x7fffffff; } } }
  for (int base = p0; base < pend; base += 8){
    STEP(A,0) STEP(B,1) STEP(C,2) STEP(D,3)
    STEP(E,4) STEP(F,5) STEP(G,6) STEP(H,7)
  }
  while (i < i0+NPB){ FLUSHI; ++i; }
  #undef PLD
  #undef FLUSH
  #undef FLUSHI
  #undef STEP
  float* pd = pooledP + (blockIdx.x & (PCOP-1)) * DH;
  atomicAdd(&pd[2*t],       q0);
  atomicAdd(&pd[2*t+1],     q1);
  atomicAdd(&pd[256+2*t],   q2);
  atomicAdd(&pd[256+2*t+1], q3);
  atomicAdd(&pd[512+2*t],   q4);
  atomicAdd(&pd[512+2*t+1], q5);
}

__global__ __launch_bounds__(256) void k_final(const float* __restrict__ pooledP,
                                               const float* __restrict__ oW,
                                               const float* __restrict__ ob,
                                               float* __restrict__ out){
  __shared__ float ps[DH];
  __shared__ float red[256];
  const int t = threadIdx.x;
  for (int h=t; h<DH; h+=256){
    float s = 0.f;
    #pragma unroll
    for (int c=0;c<PCOP;c++) s += pooledP[c*DH + h];
    ps[h] = s;
  }
  __syncthreads();
  for (int c=0;c<5;c++){
    float p = 0.f;
    for (int h=t; h<DH; h+=256) p += ps[h]*oW[c*DH + h];
    red[t] = p; __syncthreads();
    for (int o=128;o;o>>=1){ if (t<o) red[t]+=red[t+o]; __syncthreads(); }
    if (t == 0) out[c] = red[0]*(1.f/(float)NN) + ob[c];
    __syncthreads();
  }
}

// ---------------- launch ----------------
extern "C" void kernel_launch(void* const* d_in, const int* in_sizes, int n_in,
                              void* d_out, int out_size, void* d_ws, size_t ws_size,
                              hipStream_t stream)
{
  (void)in_sizes; (void)n_in; (void)out_size; (void)ws_size;
  const float* x     = (const float*)d_in[0];
  const int*   ei    = (const int*)  d_in[1];   // [2][E]: row0=src, row1=dst
  const int*   et    = (const int*)  d_in[2];
  const float* relW  = (const float*)d_in[3];
  const float* relb  = (const float*)d_in[4];
  const float* nc    = (const float*)d_in[5];
  const float* linW  = (const float*)d_in[6];
  const float* linb  = (const float*)d_in[7];
  const float* selfW = (const float*)d_in[8];
  const float* selfb = (const float*)d_in[9];
  const float* outW  = (const float*)d_in[10];
  const float* outb  = (const float*)d_in[11];
  float* out = (float*)d_out;

  // workspace layout (256B aligned); hm/selfx alias S (dead after gemm1)
  u8* w = (u8*)d_ws;
  int*   counts = (int*)(w + 0);              // 64 KB
  int*   starts = (int*)(w + 65536);          // 16385*4
  int*   cursor = (int*)(w + 131328);         // 64 KB
  int*   srcp   = (int*)(w + 196864);         // 1 MB (packed src|rel<<28)
  u16*   Wst    = (u16*)(w + 4391168);        // 768*3488*2  = 5.36 MB
  u16*   WB     = (u16*)(w + 9748736);        // 1536*768*2  = 2.36 MB
  u16*   x1     = (u16*)(w + 12108032);       // 16384*768*2 = 25.2 MB
  u16*   S      = (u16*)(w + 37276928);       // 16384*3488*2 = 114.3 MB
  u16*   hm     = S;                          // alias: 25.2 MB
  u16*   sfx    = (u16*)(w + 37276928 + 25165824);
  // partial pooled copies live in S's tail (dead after gemm1 reads S)
  float* pooledP = (float*)(w + 37276928 + 50331648);  // PCOP*768*4 = 48 KB

  const int* esrc = ei;
  const int* edst = ei + EE;

  hipMemsetAsync(counts, 0, NN*sizeof(int), stream);

  k_count <<<EE/256, 256, 0, stream>>>(edst, counts);
  k_scan  <<<1, 1024, 0, stream>>>(counts, starts, cursor);
  k_place <<<EE/256, 256, 0, stream>>>(esrc, edst, et, cursor, srcp);
  k_convW1<<<dim3(14, DH), 256, 0, stream>>>(relW, relb, Wst);
  k_convW2<<<(2*DH*DH)/256, 256, 0, stream>>>(linW, selfW, WB);
  k_phase1f<<<NN/4, 256, 0, stream>>>(x, srcp, nc, starts, S);
  k_gemmw<0,6><<<(NN/256)*(DH/128), 512, 0, stream>>>(
      S, Wst, KS, x1, (u16*)nullptr, (const float*)nullptr, (const float*)nullptr);
  // S fully consumed by gemm1; its tail is now free for the pooled partials
  hipMemsetAsync(pooledP, 0, PCOP*DH*sizeof(float), stream);
  k_gemmw<1,12><<<(NN/256)*(2*DH/128), 512, 0, stream>>>(
      x1, WB, DH, hm, sfx, linb, selfb);
  k_phase2<<<NN/NPB, 128, 0, stream>>>(hm, sfx, srcp, starts, pooledP);
  k_final <<<1, 256, 0, stream>>>(pooledP, outW, outb, out);
}

// Round 7
// 441.976 us; speedup vs baseline: 1.0483x; 1.0483x over previous
//
#include <hip/hip_runtime.h>

typedef unsigned char  u8;
typedef unsigned short u16;
typedef unsigned int   u32;

#define NN   16384     // nodes
#define EE   262144    // edges
#define RR   9         // relations
#define DIN  384
#define DH   768
#define KSU  3456      // RR*DIN
#define KS   3488      // KSU + 9 cnt cols + pad to 32
#define NPB  4         // nodes per block in phase2
#define PCOP 16        // partial pooled copies

typedef float  f32x4 __attribute__((ext_vector_type(4)));
typedef float  f32x2 __attribute__((ext_vector_type(2)));
typedef u32    u32x2 __attribute__((ext_vector_type(2)));
typedef __bf16 b16x8 __attribute__((ext_vector_type(8)));

__device__ __forceinline__ u16 f2bf(float f){
  u32 u = __builtin_bit_cast(u32, f);
  u += 0x7fffu + ((u >> 16) & 1u);          // RNE
  return (u16)(u >> 16);
}
__device__ __forceinline__ float bf2f(u16 h){
  u32 u = ((u32)h) << 16;
  return __builtin_bit_cast(float, u);
}
__device__ __forceinline__ u32 pkbf(float a, float b){
  return (u32)f2bf(a) | ((u32)f2bf(b) << 16);
}
// async global->LDS, 16B per lane; LDS dest = wave-uniform base + lane*16
__device__ __forceinline__ void gll16(const void* g, void* l){
  __builtin_amdgcn_global_load_lds((const __attribute__((address_space(1))) void*)g,
                                   (__attribute__((address_space(3))) void*)l, 16, 0, 0);
}
// DPP row rotate (16-lane rows), full-rate VALU — no LDS pipe
template<int N> __device__ __forceinline__ float dppror(float v){
  return __builtin_bit_cast(float,
    __builtin_amdgcn_update_dpp(0, __builtin_bit_cast(int, v), 0x120+N, 0xF, 0xF, true));
}
__device__ __forceinline__ float swz16(float v){   // lane ^ 16 within 32-group
  return __builtin_bit_cast(float,
    __builtin_amdgcn_ds_swizzle(__builtin_bit_cast(int, v), 0x401F));
}

// ---------------- CSR build ----------------
__global__ void k_count(const int* __restrict__ dst, int* __restrict__ counts){
  const int e = blockIdx.x*256 + threadIdx.x;
  if (e < EE) atomicAdd(&counts[dst[e]], 1);
}

__global__ __launch_bounds__(1024) void k_scan(const int* __restrict__ counts,
                                               int* __restrict__ starts,
                                               int* __restrict__ cursor){
  __shared__ int tot[1024];
  const int t = threadIdx.x;
  int loc[16]; int s = 0;
  #pragma unroll
  for (int j=0;j<16;j++){ loc[j] = counts[t*16+j]; s += loc[j]; }
  tot[t] = s;
  __syncthreads();
  for (int o=1;o<1024;o<<=1){
    int v = (t>=o) ? tot[t-o] : 0;
    __syncthreads();
    tot[t] += v;
    __syncthreads();
  }
  int run = tot[t] - s;  // exclusive prefix
  #pragma unroll
  for (int j=0;j<16;j++){ starts[t*16+j] = run; cursor[t*16+j] = run; run += loc[j]; }
  if (t == 1023) starts[NN] = run;
}

// scatter edges into CSR order; pack src | (rel<<28) into one array
__global__ void k_place(const int* __restrict__ src, const int* __restrict__ dst,
                        const int* __restrict__ et, int* __restrict__ cursor,
                        int* __restrict__ sp){
  const int e = blockIdx.x*256 + threadIdx.x;
  if (e < EE){
    const int p = atomicAdd(&cursor[dst[e]], 1);
    sp[p] = (int)(((u32)et[e] << 28) | (u32)src[e]);
  }
}

// ---------------- weight conversion to bf16 ----------------
__global__ void k_convW1(const float* __restrict__ rW, const float* __restrict__ rb,
                         u16* __restrict__ Wst){
  const int hh = blockIdx.y;
  const int k  = blockIdx.x*256 + threadIdx.x;
  if (k >= KS) return;
  float v;
  if (k < KSU){ const int r = k / DIN; const int d = k - r*DIN;
                v = rW[((long)r*DH + hh)*DIN + d]; }
  else if (k < KSU + RR){ const int r = k - KSU; v = rb[(long)r*DH + hh]; }
  else v = 0.f;
  Wst[(long)hh*KS + k] = f2bf(v);
}

__global__ void k_convW2(const float* __restrict__ lW, const float* __restrict__ sW,
                         u16* __restrict__ WB){
  const int idx = blockIdx.x*256 + threadIdx.x;  // exactly 1179648 threads
  const float v = (idx < DH*DH) ? lW[idx] : sW[idx - DH*DH];
  WB[idx] = f2bf(v);
}

// ---------------- phase1 fused: one wave per dst node, VGPR accumulators ----
__global__ __launch_bounds__(256, 3) void k_phase1f(const float* __restrict__ x,
                                                    const int* __restrict__ sp,
                                                    const float* __restrict__ nc,
                                                    const int* __restrict__ starts,
                                                    u16* __restrict__ s){
  const int wv = threadIdx.x >> 6;
  const int l  = threadIdx.x & 63;
  const int i  = blockIdx.x*4 + wv;
  const float* xdp = x + (long)i*DIN;
  const f32x4 xq = *(const f32x4*)(xdp + 4*l);
  const f32x2 xr = *(const f32x2*)(xdp + 256 + 2*l);
  float acc[RR][6];
  float cacc[RR];
  #pragma unroll
  for (int r=0;r<RR;r++){
    cacc[r] = 0.f;
    #pragma unroll
    for (int j=0;j<6;j++) acc[r][j] = 0.f;
  }
  const int e0 = starts[i], e1 = starts[i+1];
  f32x4 Aq={0,0,0,0}, Bq={0,0,0,0}, Cq={0,0,0,0}, Dq={0,0,0,0};
  f32x2 Ar={0,0}, Br={0,0}, Cr={0,0}, Dr={0,0};
  u32 qA=0,qB=0,qC=0,qD=0;
  #define LDE(S, QQ, IDX) { const int pe_=(IDX); if (pe_ < e1){ QQ = (u32)sp[pe_]; \
      const float* xs_ = x + (long)(QQ & 0x3FFFu)*DIN; \
      S##q = *(const f32x4*)(xs_ + 4*l); \
      S##r = *(const f32x2*)(xs_ + 256 + 2*l); } }
  LDE(A,qA,e0) LDE(B,qB,e0+1) LDE(C,qC,e0+2) LDE(D,qD,e0+3)
  #define DOT(uq,ur) (xq.x*uq.x + xq.y*uq.y + xq.z*uq.z + xq.w*uq.w \
                    + xr.x*ur.x + xr.y*ur.y)
  #define UPD(R,P,cq,cr) { cacc[R] += P; \
      acc[R][0] += P*cq.x; acc[R][1] += P*cq.y; acc[R][2] += P*cq.z; \
      acc[R][3] += P*cq.w; acc[R][4] += P*cr.x; acc[R][5] += P*cr.y; }
  #define SW(RQ,P,cq,cr) switch (RQ){ \
      case 0: UPD(0,P,cq,cr); break; case 1: UPD(1,P,cq,cr); break; \
      case 2: UPD(2,P,cq,cr); break; case 3: UPD(3,P,cq,cr); break; \
      case 4: UPD(4,P,cq,cr); break; case 5: UPD(5,P,cq,cr); break; \
      case 6: UPD(6,P,cq,cr); break; case 7: UPD(7,P,cq,cr); break; \
      default: UPD(8,P,cq,cr); break; }
  for (int p=e0; p<e1; p+=4){
    const f32x4 aq=Aq, bq=Bq, cq=Cq, dq=Dq;
    const f32x2 ar=Ar, br=Br, cr=Cr, dr=Dr;
    const u32 qa=qA, qb=qB, qc=qC, qd=qD;
    const bool h1 = p+1<e1, h2 = p+2<e1, h3 = p+3<e1;
    LDE(A,qA,p+4) LDE(B,qB,p+5) LDE(C,qC,p+6) LDE(D,qD,p+7)
    float pa = DOT(aq,ar), pb = DOT(bq,br);
    float pc = DOT(cq,cr), pd = DOT(dq,dr);
    // 16-lane rotate-reduce via DPP (VALU), then xor16 (swizzle), xor32 (shfl)
    pa += dppror<1>(pa); pb += dppror<1>(pb); pc += dppror<1>(pc); pd += dppror<1>(pd);
    pa += dppror<2>(pa); pb += dppror<2>(pb); pc += dppror<2>(pc); pd += dppror<2>(pd);
    pa += dppror<4>(pa); pb += dppror<4>(pb); pc += dppror<4>(pc); pd += dppror<4>(pd);
    pa += dppror<8>(pa); pb += dppror<8>(pb); pc += dppror<8>(pc); pd += dppror<8>(pd);
    pa += swz16(pa); pb += swz16(pb); pc += swz16(pc); pd += swz16(pd);
    pa += __shfl_xor(pa,32); pb += __shfl_xor(pb,32);
    pc += __shfl_xor(pc,32); pd += __shfl_xor(pd,32);
    SW(qa>>28, pa, aq,ar);
    if (h1){ SW(qb>>28, pb, bq,br); }
    if (h2){ SW(qc>>28, pc, cq,cr); }
    if (h3){ SW(qd>>28, pd, dq,dr); }
  }
  #undef LDE
  #undef DOT
  #undef UPD
  #undef SW
  u16* srow = s + (long)i*KS;
  #pragma unroll
  for (int r=0;r<RR;r++){
    const float inv = 1.0f / nc[r];
    const u32 pk0 = pkbf(acc[r][0]*inv, acc[r][1]*inv);
    const u32 pk1 = pkbf(acc[r][2]*inv, acc[r][3]*inv);
    const u32 pk2 = pkbf(acc[r][4]*inv, acc[r][5]*inv);
    *(u32x2*)(srow + r*DIN + 4*l) = (u32x2){pk0, pk1};   // cols 4l..4l+3
    ((u32*)(srow + r*DIN + 256))[l] = pk2;               // cols 256+{2l,2l+1}
  }
  float cv = 0.f;
  #pragma unroll
  for (int r=0;r<RR;r++) cv = (l == r) ? cacc[r] : cv;
  if (l < 32){
    const float invl = (l < RR) ? 1.0f/nc[l] : 0.f;
    srow[KSU + l] = f2bf(l < RR ? cv*invl : 0.f);
  }
}

// ---------------- 256x192 ring-pipelined bf16 GEMM: C = A * B^T (K-major) -----
// 512 threads = 8 waves (2 wm x 4 wn), per-wave C = 128x48 (acc[8][3] = 96 AGPR).
// GRID FILL: gemm1 = 64 m x 4 n = 256 blocks = exactly 1/CU, 100% fill, one
// round, zero tail. gemm2 = 64 x 8 = 512 = two clean full rounds.
// PIPELINE: BK=32; 5-slot LDS ring (5 x 28 KiB = 140 KiB, sole block on CU);
// prefetch distance 4 -> coverage = 2 waves/SIMD x 24 MFMA x 4.8cy x 4 = 921cy
// (R4's proven number). ONE raw s_barrier + ONE counted vmcnt per K-tile.
// STAGING BY WAVE ROLE: waves 0-3 stage A (4 gll16), waves 4-7 stage B (3);
// counted vmcnt literals are per-wave-group (12/9 steady; taper 8/6, 4/3, 0).
// T2 XOR swizzle (unit ^= (row>>1)&3) via inverse-swizzled GLOBAL source
// (gll16 dest linear) + swizzled ds_read; row-invariant per thread
// (128*wm, 48*wn, 16*i,j all = 0 mod 4 after >>1). setprio around MFMA (T5).
// Race-freedom: STAGE(tt+4) writes slot (tt+4)%5 == (tt-1)%5, whose ds_reads
// completed before the barrier ending iteration tt-1 (lgkmcnt drained before
// MFMA, which precedes that barrier).
// 1-D grid, bijective XCD-chunk swizzle (nwg%8==0, cpx%NT==0).
// MODE 0: O0 = relu(C) bf16 (gemm1) ; MODE 1: n<768 -> O0=C+b0 else O1=C+b1
template<int MODE, int NT>
__global__ __launch_bounds__(512, 2)
void k_gemmw(const u16* __restrict__ A, const u16* __restrict__ B, int K,
             u16* __restrict__ O0, u16* __restrict__ O1,
             const float* __restrict__ b0, const float* __restrict__ b1)
{
  __shared__ __align__(16) u16 lds[5][14336];   // 5 x 28 KiB = 140 KiB
  const int cpx = gridDim.x >> 3;
  const int bid = blockIdx.x;
  const int lg  = (bid & 7)*cpx + (bid >> 3);
  const int mt  = lg / NT;
  const long m0 = (long)mt * 256;
  const long n0 = (long)(lg - mt*NT) * 192;
  const int t   = threadIdx.x;
  const int wv  = t >> 6;
  const int ln  = t & 63;
  const int wm  = wv >> 2;          // 0..1
  const int wn  = wv & 3;           // 0..3
  const int fr  = ln & 15, fq = ln >> 4;

  // staging thread params: u = t&255; thread covers chunk columns kslot=u&3 of
  // rows (u>>2)+64j; global k-unit = (u&3)^((u>>3)&3) (row-invariant inverse swz)
  const int u_  = t & 255;
  const int gsl = (u_ & 3) ^ ((u_ >> 3) & 3);
  const int sr0 = u_ >> 2;

  // fragment ds_read bases (bytes within a slot); swizzle unit row-invariant
  const int su  = fq ^ ((fr >> 1) & 3);
  const int dsA = (wm*128 + fr)*64 + (su << 4);            // A region: rows 0..255
  const int dsB = 16384 + (wn*48 + fr)*64 + (su << 4);     // B region at +16 KiB

  f32x4 acc[8][3];
  #pragma unroll
  for (int i=0;i<8;i++)
    #pragma unroll
    for (int j=0;j<3;j++) acc[i][j] = {0.f,0.f,0.f,0.f};

  const int nk = K >> 5;

  #define STAGE(SL, TT) { const long k0_ = (long)(TT)*32;                           \
    u16* s_ = &lds[SL][0];                                                          \
    if (t < 256){                                                                   \
      gll16(A + (m0 + sr0      )*(long)K + k0_ + gsl*8, s_ + (wv*64      )*8);      \
      gll16(A + (m0 + sr0 +  64)*(long)K + k0_ + gsl*8, s_ + (wv*64 + 256)*8);      \
      gll16(A + (m0 + sr0 + 128)*(long)K + k0_ + gsl*8, s_ + (wv*64 + 512)*8);      \
      gll16(A + (m0 + sr0 + 192)*(long)K + k0_ + gsl*8, s_ + (wv*64 + 768)*8);      \
    } else {                                                                        \
      gll16(B + (n0 + sr0      )*(long)K + k0_ + gsl*8, s_ + 8192 + ((wv-4)*64      )*8); \
      gll16(B + (n0 + sr0 +  64)*(long)K + k0_ + gsl*8, s_ + 8192 + ((wv-4)*64 + 256)*8); \
      gll16(B + (n0 + sr0 + 128)*(long)K + k0_ + gsl*8, s_ + 8192 + ((wv-4)*64 + 512)*8); \
    } }

  #define WAITN(N4, N3) { if (wv < 4) asm volatile("s_waitcnt vmcnt(" #N4 ")" ::: "memory"); \
                          else        asm volatile("s_waitcnt vmcnt(" #N3 ")" ::: "memory"); }

  STAGE(0, 0) STAGE(1, 1) STAGE(2, 2) STAGE(3, 3)
  WAITN(12, 9)                                   // tile 0 landed; 1,2,3 in flight
  __builtin_amdgcn_s_barrier();

  int cs = 0, ps = 4;                            // compute slot, prefetch slot
  for (int tt = 0; tt < nk; ++tt){
    if (tt + 4 < nk) STAGE(ps, tt + 4)
    const u8* sl = (const u8*)&lds[cs][0];
    b16x8 av[8], bv[3];
    #pragma unroll
    for (int i=0;i<8;i++) av[i] = *(const b16x8*)(sl + dsA + i*1024);
    #pragma unroll
    for (int j=0;j<3;j++) bv[j] = *(const b16x8*)(sl + dsB + j*1024);
    __builtin_amdgcn_s_setprio(1);
    #pragma unroll
    for (int i=0;i<8;i++)
      #pragma unroll
      for (int j=0;j<3;j++)
        acc[i][j] = __builtin_amdgcn_mfma_f32_16x16x32_bf16(av[i], bv[j], acc[i][j], 0, 0, 0);
    __builtin_amdgcn_s_setprio(0);
    if (tt + 4 < nk)      WAITN(12, 9)           // next tile ready; 3 stages fly
    else if (tt + 3 < nk) WAITN(8, 6)
    else if (tt + 2 < nk) WAITN(4, 3)
    else if (tt + 1 < nk) WAITN(0, 0)
    __builtin_amdgcn_s_barrier();
    cs = (cs == 4) ? 0 : cs + 1;
    ps = (ps == 4) ? 0 : ps + 1;
  }
  #undef STAGE
  #undef WAITN

  #pragma unroll
  for (int i=0;i<8;i++){
    #pragma unroll
    for (int j=0;j<3;j++){
      #pragma unroll
      for (int r=0;r<4;r++){
        const long m = m0 + wm*128 + i*16 + fq*4 + r;   // C row = quad*4+reg
        const long n = n0 + wn*48  + j*16 + fr;         // C col = lane&15
        float v = acc[i][j][r];
        if (MODE == 0){
          v = v > 0.f ? v : 0.f;
          O0[m*DH + n] = f2bf(v);
        } else {
          if (n < DH) O0[m*DH + n]      = f2bf(v + b0[n]);
          else        O1[m*DH + (n-DH)] = f2bf(v + b1[n-DH]);
        }
      }
    }
  }
}

// ---------------- phase2 fused with mean-pool: aggr2 + self + relu -> pooled ----
__global__ __launch_bounds__(128) void k_phase2(const u16* __restrict__ hm,
                                                const u16* __restrict__ sfx,
                                                const int* __restrict__ sp,
                                                const int* __restrict__ starts,
                                                float* __restrict__ pooledP){
  const int t  = threadIdx.x;
  const int i0 = blockIdx.x * NPB;
  const int p0 = starts[i0];
  const int pend = starts[i0 + NPB];
  u32 sf00,sf01,sf02, sf10,sf11,sf12, sf20,sf21,sf22, sf30,sf31,sf32;
  { const u32* sr = (const u32*)(sfx + (long)(i0+0)*DH); sf00=sr[t]; sf01=sr[t+128]; sf02=sr[t+256]; }
  { const u32* sr = (const u32*)(sfx + (long)(i0+1)*DH); sf10=sr[t]; sf11=sr[t+128]; sf12=sr[t+256]; }
  { const u32* sr = (const u32*)(sfx + (long)(i0+2)*DH); sf20=sr[t]; sf21=sr[t+128]; sf22=sr[t+256]; }
  { const u32* sr = (const u32*)(sfx + (long)(i0+3)*DH); sf30=sr[t]; sf31=sr[t+128]; sf32=sr[t+256]; }
  u32 A0=0,A1=0,A2=0,B0=0,B1=0,B2=0,C0=0,C1=0,C2=0,D0=0,D1=0,D2=0;
  u32 E0=0,E1=0,E2=0,F0=0,F1=0,F2=0,G0=0,G1=0,G2=0,H0=0,H1=0,H2=0;
  #define PLD(S, IDX) { const int nf_=(IDX); if (nf_ < pend){ \
      const u32* hr_ = (const u32*)(hm + (long)(((u32)sp[nf_]) & 0x3FFFu)*DH); \
      S##0=hr_[t]; S##1=hr_[t+128]; S##2=hr_[t+256]; } }
  PLD(A,p0)   PLD(B,p0+1) PLD(C,p0+2) PLD(D,p0+3)
  PLD(E,p0+4) PLD(F,p0+5) PLD(G,p0+6) PLD(H,p0+7)
  float a0=0.f,a1=0.f,a2=0.f,a3=0.f,a4=0.f,a5=0.f;
  float q0=0.f,q1=0.f,q2=0.f,q3=0.f,q4=0.f,q5=0.f;
  int i = i0;
  int e1 = starts[i0+1];
  #define FLUSH(K) { float v_; \
    v_=a0+bf2f((u16)sf##K##0);        q0+=fmaxf(v_,0.f); \
    v_=a1+bf2f((u16)(sf##K##0>>16));  q1+=fmaxf(v_,0.f); \
    v_=a2+bf2f((u16)sf##K##1);        q2+=fmaxf(v_,0.f); \
    v_=a3+bf2f((u16)(sf##K##1>>16));  q3+=fmaxf(v_,0.f); \
    v_=a4+bf2f((u16)sf##K##2);        q4+=fmaxf(v_,0.f); \
    v_=a5+bf2f((u16)(sf##K##2>>16));  q5+=fmaxf(v_,0.f); \
    a0=a1=a2=a3=a4=a5=0.f; }
  #define FLUSHI { switch (i - i0){ case 0: FLUSH(0); break; case 1: FLUSH(1); break; \
                   case 2: FLUSH(2); break; default: FLUSH(3); break; } }
  while (i < i0+NPB && e1 == p0){ FLUSHI; ++i; e1 = (i < i0+NPB) ? starts[i+1] : 0x7fffffff; }
  #define STEP(S, K) { const int pe_ = base + K; if (pe_ < pend){ \
      const u32 d0_=S##0, d1_=S##1, d2_=S##2; \
      PLD(S, pe_ + 8); \
      a0+=bf2f((u16)d0_); a1+=bf2f((u16)(d0_>>16)); \
      a2+=bf2f((u16)d1_); a3+=bf2f((u16)(d1_>>16)); \
      a4+=bf2f((u16)d2_); a5+=bf2f((u16)(d2_>>16)); \
      while (i < i0+NPB && pe_+1 == e1){ FLUSHI; ++i; \
        e1 = (i < i0+NPB) ? starts[i+1] : 0x7fffffff; } } }
  for (int base = p0; base < pend; base += 8){
    STEP(A,0) STEP(B,1) STEP(C,2) STEP(D,3)
    STEP(E,4) STEP(F,5) STEP(G,6) STEP(H,7)
  }
  while (i < i0+NPB){ FLUSHI; ++i; }
  #undef PLD
  #undef FLUSH
  #undef FLUSHI
  #undef STEP
  float* pd = pooledP + (blockIdx.x & (PCOP-1)) * DH;
  atomicAdd(&pd[2*t],       q0);
  atomicAdd(&pd[2*t+1],     q1);
  atomicAdd(&pd[256+2*t],   q2);
  atomicAdd(&pd[256+2*t+1], q3);
  atomicAdd(&pd[512+2*t],   q4);
  atomicAdd(&pd[512+2*t+1], q5);
}

__global__ __launch_bounds__(256) void k_final(const float* __restrict__ pooledP,
                                               const float* __restrict__ oW,
                                               const float* __restrict__ ob,
                                               float* __restrict__ out){
  __shared__ float ps[DH];
  __shared__ float red[256];
  const int t = threadIdx.x;
  for (int h=t; h<DH; h+=256){
    float s = 0.f;
    #pragma unroll
    for (int c=0;c<PCOP;c++) s += pooledP[c*DH + h];
    ps[h] = s;
  }
  __syncthreads();
  for (int c=0;c<5;c++){
    float p = 0.f;
    for (int h=t; h<DH; h+=256) p += ps[h]*oW[c*DH + h];
    red[t] = p; __syncthreads();
    for (int o=128;o;o>>=1){ if (t<o) red[t]+=red[t+o]; __syncthreads(); }
    if (t == 0) out[c] = red[0]*(1.f/(float)NN) + ob[c];
    __syncthreads();
  }
}

// ---------------- launch ----------------
extern "C" void kernel_launch(void* const* d_in, const int* in_sizes, int n_in,
                              void* d_out, int out_size, void* d_ws, size_t ws_size,
                              hipStream_t stream)
{
  (void)in_sizes; (void)n_in; (void)out_size; (void)ws_size;
  const float* x     = (const float*)d_in[0];
  const int*   ei    = (const int*)  d_in[1];   // [2][E]: row0=src, row1=dst
  const int*   et    = (const int*)  d_in[2];
  const float* relW  = (const float*)d_in[3];
  const float* relb  = (const float*)d_in[4];
  const float* nc    = (const float*)d_in[5];
  const float* linW  = (const float*)d_in[6];
  const float* linb  = (const float*)d_in[7];
  const float* selfW = (const float*)d_in[8];
  const float* selfb = (const float*)d_in[9];
  const float* outW  = (const float*)d_in[10];
  const float* outb  = (const float*)d_in[11];
  float* out = (float*)d_out;

  // workspace layout (256B aligned); hm/selfx alias S (dead after gemm1)
  u8* w = (u8*)d_ws;
  int*   counts = (int*)(w + 0);              // 64 KB
  int*   starts = (int*)(w + 65536);          // 16385*4
  int*   cursor = (int*)(w + 131328);         // 64 KB
  int*   srcp   = (int*)(w + 196864);         // 1 MB (packed src|rel<<28)
  u16*   Wst    = (u16*)(w + 4391168);        // 768*3488*2  = 5.36 MB
  u16*   WB     = (u16*)(w + 9748736);        // 1536*768*2  = 2.36 MB
  u16*   x1     = (u16*)(w + 12108032);       // 16384*768*2 = 25.2 MB
  u16*   S      = (u16*)(w + 37276928);       // 16384*3488*2 = 114.3 MB
  u16*   hm     = S;                          // alias: 25.2 MB
  u16*   sfx    = (u16*)(w + 37276928 + 25165824);
  // partial pooled copies live in S's tail (dead after gemm1 reads S)
  float* pooledP = (float*)(w + 37276928 + 50331648);  // PCOP*768*4 = 48 KB

  const int* esrc = ei;
  const int* edst = ei + EE;

  hipMemsetAsync(counts, 0, NN*sizeof(int), stream);

  k_count <<<EE/256, 256, 0, stream>>>(edst, counts);
  k_scan  <<<1, 1024, 0, stream>>>(counts, starts, cursor);
  k_place <<<EE/256, 256, 0, stream>>>(esrc, edst, et, cursor, srcp);
  k_convW1<<<dim3(14, DH), 256, 0, stream>>>(relW, relb, Wst);
  k_convW2<<<(2*DH*DH)/256, 256, 0, stream>>>(linW, selfW, WB);
  k_phase1f<<<NN/4, 256, 0, stream>>>(x, srcp, nc, starts, S);
  k_gemmw<0,4><<<(NN/256)*(DH/192), 512, 0, stream>>>(
      S, Wst, KS, x1, (u16*)nullptr, (const float*)nullptr, (const float*)nullptr);
  // S fully consumed by gemm1; its tail is now free for the pooled partials
  hipMemsetAsync(pooledP, 0, PCOP*DH*sizeof(float), stream);
  k_gemmw<1,8><<<(NN/256)*(2*DH/192), 512, 0, stream>>>(
      x1, WB, DH, hm, sfx, linb, selfb);
  k_phase2<<<NN/NPB, 128, 0, stream>>>(hm, sfx, srcp, starts, pooledP);
  k_final <<<1, 256, 0, stream>>>(pooledP, outW, outb, out);
}